// Round 1
// baseline (27999.826 us; speedup 1.0000x reference)
//
#include <hip/hip_runtime.h>
#include <hip/hip_bf16.h>
#include <math.h>

#define D_MODEL 512
#define N_HEADS 8
#define D_HEAD 64
#define N_LAYERS 6
#define D_FF 2048
#define VOCAB 50257
#define ENC_LEN 2048
#define DEC_LEN 1024

// ---------------------------------------------------------------------------
// Embedding lookup + sinusoidal positional encoding
// grid: (S), block: (512) -- one thread per feature dim
// ---------------------------------------------------------------------------
__global__ __launch_bounds__(512) void embed_pe_kernel(
    const int* __restrict__ ids, const float* __restrict__ dict,
    float* __restrict__ out) {
  int s = blockIdx.x;
  int d = threadIdx.x;
  float v = dict[(long)ids[s] * D_MODEL + d];
  float expo = (float)(d & ~1) / (float)D_MODEL;
  // 10000^(-expo) = exp(-expo * ln(10000))
  float ang = (float)s * expf(-expo * 9.210340371976184f);
  v += (d & 1) ? cosf(ang) : sinf(ang);
  out[(long)s * D_MODEL + d] = v;
}

// ---------------------------------------------------------------------------
// Tiled fp32 GEMM: C[M,N] = A[M,K] @ B[K,N]   (optionally ReLU)
// M multiple of 64, K multiple of 16, N arbitrary (guarded).
// 64x64 tile, BK=16, 256 threads, 4x4 micro-tile per thread.
// LDS laid out so compute reads are float4 (ds_read_b128).
// ---------------------------------------------------------------------------
template <int RELU>
__global__ __launch_bounds__(256) void gemm_kernel(
    const float* __restrict__ A, int lda,
    const float* __restrict__ B, int ldb,
    float* __restrict__ C, int ldc,
    int N, int K) {
  __shared__ float As[16][68];  // [k][m], padded
  __shared__ float Bs[16][64];  // [k][n]

  const int bn = blockIdx.x, bm = blockIdx.y;
  const int tid = threadIdx.x;
  const int tx = tid & 15;       // 0..15 -> col group
  const int ty = tid >> 4;       // 0..15 -> row group

  // A tile load mapping: each thread one float4 along k
  const int arow = tid >> 2;          // 0..63
  const int acol4 = (tid & 3) * 4;    // 0,4,8,12
  const float* Abase = A + (long)(bm * 64 + arow) * lda + acol4;

  // B tile load mapping: 16 rows x 64 cols, scalar guarded loads
  const int br = tid >> 4;   // 0..15 (k row)
  const int bc = tid & 15;   // 0..15 (col base, +j*16)

  float acc[4][4];
#pragma unroll
  for (int i = 0; i < 4; ++i)
#pragma unroll
    for (int j = 0; j < 4; ++j) acc[i][j] = 0.0f;

  for (int k0 = 0; k0 < K; k0 += 16) {
    // --- load A 64x16 ---
    float4 av = *(const float4*)(Abase + k0);
    As[acol4 + 0][arow] = av.x;
    As[acol4 + 1][arow] = av.y;
    As[acol4 + 2][arow] = av.z;
    As[acol4 + 3][arow] = av.w;
    // --- load B 16x64 (guarded on N) ---
    {
      const float* Bp = B + (long)(k0 + br) * ldb + bn * 64 + bc;
#pragma unroll
      for (int j = 0; j < 4; ++j) {
        int col = bn * 64 + bc + j * 16;
        Bs[br][bc + j * 16] = (col < N) ? Bp[j * 16] : 0.0f;
      }
    }
    __syncthreads();
#pragma unroll
    for (int kk = 0; kk < 16; ++kk) {
      float4 a = *(const float4*)&As[kk][ty * 4];
      float4 b = *(const float4*)&Bs[kk][tx * 4];
      acc[0][0] += a.x * b.x; acc[0][1] += a.x * b.y;
      acc[0][2] += a.x * b.z; acc[0][3] += a.x * b.w;
      acc[1][0] += a.y * b.x; acc[1][1] += a.y * b.y;
      acc[1][2] += a.y * b.z; acc[1][3] += a.y * b.w;
      acc[2][0] += a.z * b.x; acc[2][1] += a.z * b.y;
      acc[2][2] += a.z * b.z; acc[2][3] += a.z * b.w;
      acc[3][0] += a.w * b.x; acc[3][1] += a.w * b.y;
      acc[3][2] += a.w * b.z; acc[3][3] += a.w * b.w;
    }
    __syncthreads();
  }

#pragma unroll
  for (int i = 0; i < 4; ++i) {
    int row = bm * 64 + ty * 4 + i;
    float* Cp = C + (long)row * ldc + bn * 64 + tx * 4;
#pragma unroll
    for (int j = 0; j < 4; ++j) {
      int col = bn * 64 + tx * 4 + j;
      if (col < N) {
        float v = acc[i][j];
        if (RELU) v = fmaxf(v, 0.0f);
        Cp[j] = v;
      }
    }
  }
}

// ---------------------------------------------------------------------------
// Fused attention for one (query row, head): scores -> softmax -> out
// grid: (Sq, H), block: 256.  Q/K/V given with row strides; head offset h*64.
// causal: keys j > qi masked out (equivalent to ref's -1e9 additive mask).
// ---------------------------------------------------------------------------
__global__ __launch_bounds__(256) void attn_kernel(
    const float* __restrict__ Q, int ldq,
    const float* __restrict__ K, int ldk,
    const float* __restrict__ V, int ldv,
    float* __restrict__ O, int ldo,
    int Sk, int causal) {
  __shared__ float sc[ENC_LEN];
  __shared__ float qs[D_HEAD];
  __shared__ float red[4];
  __shared__ float part[4][D_HEAD];

  const int qi = blockIdx.x;
  const int h = blockIdx.y;
  const int tid = threadIdx.x;

  if (tid < D_HEAD) qs[tid] = Q[(long)qi * ldq + h * D_HEAD + tid];
  __syncthreads();

  const int kend = causal ? (qi + 1) : Sk;

  // --- scores ---
  float lmax = -1e30f;
  for (int j = tid; j < kend; j += 256) {
    const float* kr = K + (long)j * ldk + h * D_HEAD;
    float acc = 0.0f;
#pragma unroll
    for (int d = 0; d < D_HEAD; ++d) acc += qs[d] * kr[d];
    float sv = acc * 0.125f;  // 1/sqrt(64)
    sc[j] = sv;
    lmax = fmaxf(lmax, sv);
  }
#pragma unroll
  for (int off = 1; off < 64; off <<= 1)
    lmax = fmaxf(lmax, __shfl_xor(lmax, off));
  if ((tid & 63) == 0) red[tid >> 6] = lmax;
  __syncthreads();
  const float mx = fmaxf(fmaxf(red[0], red[1]), fmaxf(red[2], red[3]));

  // --- exp + sum ---
  float lsum = 0.0f;
  for (int j = tid; j < kend; j += 256) {
    float e = __expf(sc[j] - mx);
    sc[j] = e;
    lsum += e;
  }
#pragma unroll
  for (int off = 1; off < 64; off <<= 1) lsum += __shfl_xor(lsum, off);
  __syncthreads();  // protect red (mx) reads before overwrite
  if ((tid & 63) == 0) red[tid >> 6] = lsum;
  __syncthreads();
  const float inv = 1.0f / (red[0] + red[1] + red[2] + red[3]);

  // --- output: out[d] = sum_j w_j * V[j][d] ---
  const int grp = tid >> 6;    // 0..3, key partition
  const int lane = tid & 63;   // feature dim
  float acc = 0.0f;
  for (int j = grp; j < kend; j += 4)
    acc += sc[j] * V[(long)j * ldv + h * D_HEAD + lane];
  part[grp][lane] = acc;
  __syncthreads();
  if (grp == 0) {
    float o = (part[0][lane] + part[1][lane] + part[2][lane] + part[3][lane]) * inv;
    O[(long)qi * ldo + h * D_HEAD + lane] = o;
  }
}

// ---------------------------------------------------------------------------
// x = layernorm(x + y)  (no affine, eps=1e-6), rows of 512
// grid: (S), block: 256 (2 elements per thread)
// ---------------------------------------------------------------------------
__global__ __launch_bounds__(256) void add_norm_kernel(
    float* __restrict__ x, const float* __restrict__ y) {
  __shared__ float red[4];
  const int row = blockIdx.x;
  const int tid = threadIdx.x;
  float* xr = x + (long)row * D_MODEL;
  const float* yr = y + (long)row * D_MODEL;

  float v0 = xr[tid] + yr[tid];
  float v1 = xr[tid + 256] + yr[tid + 256];

  float s = v0 + v1;
#pragma unroll
  for (int off = 1; off < 64; off <<= 1) s += __shfl_xor(s, off);
  if ((tid & 63) == 0) red[tid >> 6] = s;
  __syncthreads();
  const float mean = (red[0] + red[1] + red[2] + red[3]) * (1.0f / D_MODEL);

  float d0 = v0 - mean, d1 = v1 - mean;
  float vs = d0 * d0 + d1 * d1;
#pragma unroll
  for (int off = 1; off < 64; off <<= 1) vs += __shfl_xor(vs, off);
  __syncthreads();  // protect mean reads
  if ((tid & 63) == 0) red[tid >> 6] = vs;
  __syncthreads();
  const float var = (red[0] + red[1] + red[2] + red[3]) * (1.0f / D_MODEL);
  const float rn = rsqrtf(var + 1e-6f);
  xr[tid] = d0 * rn;
  xr[tid + 256] = d1 * rn;
}

// ---------------------------------------------------------------------------
extern "C" void kernel_launch(void* const* d_in, const int* in_sizes, int n_in,
                              void* d_out, int out_size, void* d_ws, size_t ws_size,
                              hipStream_t stream) {
  const int* input_ids   = (const int*)d_in[0];
  const int* dec_ids     = (const int*)d_in[1];
  const float* dict      = (const float*)d_in[2];
  const float* mh_input  = (const float*)d_in[3];
  const float* wo_input  = (const float*)d_in[4];
  const float* mh_masked = (const float*)d_in[5];
  const float* wo_masked = (const float*)d_in[6];
  const float* mh_output = (const float*)d_in[7];
  const float* wo_output = (const float*)d_in[8];
  const float* ff_in_w1  = (const float*)d_in[9];
  const float* ff_in_w2  = (const float*)d_in[10];
  const float* ff_out_w1 = (const float*)d_in[11];
  const float* ff_out_w2 = (const float*)d_in[12];
  const float* last_lin  = (const float*)d_in[13];
  float* out = (float*)d_out;

  // workspace layout (floats); total ~11.01M floats = ~44 MB
  float* ws  = (float*)d_ws;
  float* enc = ws;                              // 2048*512
  float* dec = enc + ENC_LEN * D_MODEL;         // 1024*512
  float* qkv = dec + DEC_LEN * D_MODEL;         // 2048*1536 region
  float* att = qkv + (long)ENC_LEN * 3 * D_MODEL;  // 2048*512
  float* prj = att + ENC_LEN * D_MODEL;         // 2048*512
  float* hid = prj + ENC_LEN * D_MODEL;         // 2048*2048

  auto gemm = [&](const float* A, int lda, const float* B, int ldb,
                  float* C, int ldc, int M, int N, int K, bool relu) {
    dim3 g((N + 63) / 64, M / 64), b(256);
    if (relu)
      gemm_kernel<1><<<g, b, 0, stream>>>(A, lda, B, ldb, C, ldc, N, K);
    else
      gemm_kernel<0><<<g, b, 0, stream>>>(A, lda, B, ldb, C, ldc, N, K);
  };

  // ===== Encoder =====
  embed_pe_kernel<<<ENC_LEN, D_MODEL, 0, stream>>>(input_ids, dict, enc);
  for (int l = 0; l < N_LAYERS; ++l) {
    const float* W = mh_input + (long)l * D_MODEL * 3 * D_MODEL;
    gemm(enc, D_MODEL, W, 3 * D_MODEL, qkv, 3 * D_MODEL,
         ENC_LEN, 3 * D_MODEL, D_MODEL, false);
    attn_kernel<<<dim3(ENC_LEN, N_HEADS), 256, 0, stream>>>(
        qkv, 3 * D_MODEL, qkv + D_MODEL, 3 * D_MODEL, qkv + 2 * D_MODEL,
        3 * D_MODEL, att, D_MODEL, ENC_LEN, 0);
    gemm(att, D_MODEL, wo_input + (long)l * D_MODEL * D_MODEL, D_MODEL,
         prj, D_MODEL, ENC_LEN, D_MODEL, D_MODEL, false);
    add_norm_kernel<<<ENC_LEN, 256, 0, stream>>>(enc, prj);
    gemm(enc, D_MODEL, ff_in_w1 + (long)l * D_MODEL * D_FF, D_FF,
         hid, D_FF, ENC_LEN, D_FF, D_MODEL, true);
    gemm(hid, D_FF, ff_in_w2 + (long)l * D_FF * D_MODEL, D_MODEL,
         prj, D_MODEL, ENC_LEN, D_MODEL, D_FF, false);
    add_norm_kernel<<<ENC_LEN, 256, 0, stream>>>(enc, prj);
  }

  // ===== Decoder =====
  embed_pe_kernel<<<DEC_LEN, D_MODEL, 0, stream>>>(dec_ids, dict, dec);
  float* qb = qkv;                        // 1024*512
  float* kb = qkv + DEC_LEN * D_MODEL;    // 2048*512
  float* vb = kb + ENC_LEN * D_MODEL;     // 2048*512
  for (int l = 0; l < N_LAYERS; ++l) {
    // masked self-attention
    const float* Wm = mh_masked + (long)l * D_MODEL * 3 * D_MODEL;
    gemm(dec, D_MODEL, Wm, 3 * D_MODEL, qkv, 3 * D_MODEL,
         DEC_LEN, 3 * D_MODEL, D_MODEL, false);
    attn_kernel<<<dim3(DEC_LEN, N_HEADS), 256, 0, stream>>>(
        qkv, 3 * D_MODEL, qkv + D_MODEL, 3 * D_MODEL, qkv + 2 * D_MODEL,
        3 * D_MODEL, att, D_MODEL, DEC_LEN, 1);
    gemm(att, D_MODEL, wo_masked + (long)l * D_MODEL * D_MODEL, D_MODEL,
         prj, D_MODEL, DEC_LEN, D_MODEL, D_MODEL, false);
    add_norm_kernel<<<DEC_LEN, 256, 0, stream>>>(dec, prj);
    // cross-attention (q from dec, k/v from enc)
    const float* Wc = mh_output + (long)l * D_MODEL * 3 * D_MODEL;
    gemm(dec, D_MODEL, Wc, 3 * D_MODEL, qb, D_MODEL,
         DEC_LEN, D_MODEL, D_MODEL, false);
    gemm(enc, D_MODEL, Wc + D_MODEL, 3 * D_MODEL, kb, D_MODEL,
         ENC_LEN, D_MODEL, D_MODEL, false);
    gemm(enc, D_MODEL, Wc + 2 * D_MODEL, 3 * D_MODEL, vb, D_MODEL,
         ENC_LEN, D_MODEL, D_MODEL, false);
    attn_kernel<<<dim3(DEC_LEN, N_HEADS), 256, 0, stream>>>(
        qb, D_MODEL, kb, D_MODEL, vb, D_MODEL, att, D_MODEL, ENC_LEN, 0);
    gemm(att, D_MODEL, wo_output + (long)l * D_MODEL * D_MODEL, D_MODEL,
         prj, D_MODEL, DEC_LEN, D_MODEL, D_MODEL, false);
    add_norm_kernel<<<DEC_LEN, 256, 0, stream>>>(dec, prj);
    // FFN
    gemm(dec, D_MODEL, ff_out_w1 + (long)l * D_MODEL * D_FF, D_FF,
         hid, D_FF, DEC_LEN, D_FF, D_MODEL, true);
    gemm(hid, D_FF, ff_out_w2 + (long)l * D_FF * D_MODEL, D_MODEL,
         prj, D_MODEL, DEC_LEN, D_MODEL, D_FF, false);
    add_norm_kernel<<<DEC_LEN, 256, 0, stream>>>(dec, prj);
  }

  // ===== Final projection to vocab =====
  gemm(dec, D_MODEL, last_lin, VOCAB, out, VOCAB, DEC_LEN, VOCAB, D_MODEL, false);
}